// Round 3
// baseline (410.733 us; speedup 1.0000x reference)
//
#include <hip/hip_runtime.h>

// TPlanesEnc: B=4, N=131072, P=512, F=32
// coords: [M,3] f32 in [-1,1]; tplanes: [3,P,P,F] f32; out: [M,3*F] f32
//
// R3 = R2 with the nontemporal-store compile fix (ext_vector_type(4) float).
// Strategy: Morton-bucket points (16^3 grid) so concurrently-resident waves
// touch an L2-sized texel neighborhood; XCD-contiguous block swizzle;
// non-temporal output stores to keep the 201 MB write stream out of L2.

#define PS 512
#define FDIM 32
#define GRID1D 16
#define NCELLS (GRID1D * GRID1D * GRID1D)   // 4096

typedef float f32x4 __attribute__((ext_vector_type(4)));

// ---- helpers ----------------------------------------------------------
__device__ __forceinline__ int cell_of(float c01) {
    int i = (int)(c01 * (float)GRID1D);
    return min(max(i, 0), GRID1D - 1);
}

__device__ __forceinline__ unsigned part3_4(unsigned x) {
    // spread 4 bits to positions 0,3,6,9
    x = (x | (x << 4)) & 0xC3u;   // bits 0,1,6,7
    x = (x | (x << 2)) & 0x249u;  // bits 0,3,6,9
    return x;
}

__device__ __forceinline__ unsigned morton12(int ix, int iy, int iz) {
    return part3_4((unsigned)ix) | (part3_4((unsigned)iy) << 1) | (part3_4((unsigned)iz) << 2);
}

__device__ __forceinline__ unsigned key_of_point(const float* __restrict__ coords, int p,
                                                 float& cx, float& cy, float& cz) {
    cx = coords[p * 3 + 0] * 0.5f + 0.5f;
    cy = coords[p * 3 + 1] * 0.5f + 0.5f;
    cz = coords[p * 3 + 2] * 0.5f + 0.5f;
    return morton12(cell_of(cx), cell_of(cy), cell_of(cz));
}

// ---- pass 1: histogram ------------------------------------------------
__global__ __launch_bounds__(256) void k_hist(const float* __restrict__ coords,
                                              unsigned* __restrict__ hist, int M) {
    int p = blockIdx.x * blockDim.x + threadIdx.x;
    if (p >= M) return;
    float cx, cy, cz;
    unsigned key = key_of_point(coords, p, cx, cy, cz);
    atomicAdd(&hist[key], 1u);
}

// ---- pass 2: exclusive scan over 4096 cells (single block) ------------
__global__ __launch_bounds__(1024) void k_scan(unsigned* __restrict__ hist) {
    __shared__ unsigned part[1024];
    int t = threadIdx.x;
    unsigned v0 = hist[t * 4 + 0];
    unsigned v1 = hist[t * 4 + 1];
    unsigned v2 = hist[t * 4 + 2];
    unsigned v3 = hist[t * 4 + 3];
    unsigned local = v0 + v1 + v2 + v3;
    part[t] = local;
    __syncthreads();
    for (int off = 1; off < 1024; off <<= 1) {
        unsigned x = (t >= off) ? part[t - off] : 0u;
        __syncthreads();
        part[t] += x;
        __syncthreads();
    }
    unsigned excl = part[t] - local;
    hist[t * 4 + 0] = excl;
    hist[t * 4 + 1] = excl + v0;
    hist[t * 4 + 2] = excl + v0 + v1;
    hist[t * 4 + 3] = excl + v0 + v1 + v2;
}

// ---- pass 3: scatter into sorted order --------------------------------
// scoords[slot] = {cx, cy, cz, bit_cast(original_point_index)}
__global__ __launch_bounds__(256) void k_scatter(const float* __restrict__ coords,
                                                 unsigned* __restrict__ offs,
                                                 float4* __restrict__ scoords, int M) {
    int p = blockIdx.x * blockDim.x + threadIdx.x;
    if (p >= M) return;
    float cx, cy, cz;
    unsigned key = key_of_point(coords, p, cx, cy, cz);
    unsigned slot = atomicAdd(&offs[key], 1u);
    float4 v;
    v.x = cx; v.y = cy; v.z = cz; v.w = __int_as_float(p);
    scoords[slot] = v;
}

// ---- pass 4: main bilerp kernel (sorted order, XCD swizzle) -----------
__global__ __launch_bounds__(256) void k_main(const float4* __restrict__ scoords,
                                              const float* __restrict__ tplanes,
                                              float* __restrict__ out, int M) {
    // XCD-contiguous remap: each of 8 XCDs gets a contiguous Morton range.
    int nb = gridDim.x;            // divisible by 8
    int chunkB = nb >> 3;
    int b = blockIdx.x;
    int b2 = (b & 7) * chunkB + (b >> 3);
    int tid = b2 * 256 + (int)threadIdx.x;

    int chunk = tid & 7;           // which float4 of F=32
    int pp = tid >> 3;
    int plane = pp % 3;
    int spos = pp / 3;
    if (spos >= M) return;

    float4 c4 = scoords[spos];
    int p = __float_as_int(c4.w);

    // plane 0: (x,y); plane 1: (x,z); plane 2: (z,y)
    float u = (plane == 2) ? c4.z : c4.x;
    float v = (plane == 1) ? c4.z : c4.y;

    float x = fminf(fmaxf(u * (float)PS - 0.5f, 0.0f), (float)(PS - 1));
    float y = fminf(fmaxf(v * (float)PS - 0.5f, 0.0f), (float)(PS - 1));
    float x0f = floorf(x);
    float y0f = floorf(y);
    int xi0 = (int)x0f;
    int yi0 = (int)y0f;
    int xi1 = min(xi0 + 1, PS - 1);
    int yi1 = min(yi0 + 1, PS - 1);
    float fx = x - x0f;
    float fy = y - y0f;

    const float4* base = (const float4*)(tplanes + (size_t)plane * PS * PS * FDIM);
    int o00 = (yi0 * PS + xi0) * 8 + chunk;
    int o01 = (yi0 * PS + xi1) * 8 + chunk;
    int o10 = (yi1 * PS + xi0) * 8 + chunk;
    int o11 = (yi1 * PS + xi1) * 8 + chunk;

    float4 f00 = base[o00];
    float4 f01 = base[o01];
    float4 f10 = base[o10];
    float4 f11 = base[o11];

    float gx = 1.0f - fx;
    float gy = 1.0f - fy;
    f32x4 r;
    r.x = (f00.x * gx + f01.x * fx) * gy + (f10.x * gx + f11.x * fx) * fy;
    r.y = (f00.y * gx + f01.y * fx) * gy + (f10.y * gx + f11.y * fx) * fy;
    r.z = (f00.z * gx + f01.z * fx) * gy + (f10.z * gx + f11.z * fx) * fy;
    r.w = (f00.w * gx + f01.w * fx) * gy + (f10.w * gx + f11.w * fx) * fy;

    // out[p][plane*32 + chunk*4 ..] as float4: index p*24 + plane*8 + chunk
    f32x4* outv = (f32x4*)out;
    __builtin_nontemporal_store(r, &outv[(size_t)p * 24 + plane * 8 + chunk]);
}

// ---- fallback direct kernel (if ws too small) -------------------------
__global__ __launch_bounds__(256) void k_direct(const float* __restrict__ coords,
                                                const float* __restrict__ tplanes,
                                                float* __restrict__ out, int M) {
    int tid = blockIdx.x * blockDim.x + threadIdx.x;
    int total = M * 3 * (FDIM / 4);
    if (tid >= total) return;
    int chunk = tid & 7;
    int pp = tid >> 3;
    int plane = pp % 3;
    int point = pp / 3;
    float cx = coords[point * 3 + 0] * 0.5f + 0.5f;
    float cy = coords[point * 3 + 1] * 0.5f + 0.5f;
    float cz = coords[point * 3 + 2] * 0.5f + 0.5f;
    float u = (plane == 2) ? cz : cx;
    float v = (plane == 1) ? cz : cy;
    float x = fminf(fmaxf(u * (float)PS - 0.5f, 0.0f), (float)(PS - 1));
    float y = fminf(fmaxf(v * (float)PS - 0.5f, 0.0f), (float)(PS - 1));
    float x0f = floorf(x);
    float y0f = floorf(y);
    int xi0 = (int)x0f, yi0 = (int)y0f;
    int xi1 = min(xi0 + 1, PS - 1), yi1 = min(yi0 + 1, PS - 1);
    float fx = x - x0f, fy = y - y0f;
    const float4* base = (const float4*)(tplanes + (size_t)plane * PS * PS * FDIM);
    float4 f00 = base[(yi0 * PS + xi0) * 8 + chunk];
    float4 f01 = base[(yi0 * PS + xi1) * 8 + chunk];
    float4 f10 = base[(yi1 * PS + xi0) * 8 + chunk];
    float4 f11 = base[(yi1 * PS + xi1) * 8 + chunk];
    float gx = 1.0f - fx, gy = 1.0f - fy;
    float4 r;
    r.x = (f00.x * gx + f01.x * fx) * gy + (f10.x * gx + f11.x * fx) * fy;
    r.y = (f00.y * gx + f01.y * fx) * gy + (f10.y * gx + f11.y * fx) * fy;
    r.z = (f00.z * gx + f01.z * fx) * gy + (f10.z * gx + f11.z * fx) * fy;
    r.w = (f00.w * gx + f01.w * fx) * gy + (f10.w * gx + f11.w * fx) * fy;
    ((float4*)out)[(size_t)pp * 8 + chunk] = r;
}

extern "C" void kernel_launch(void* const* d_in, const int* in_sizes, int n_in,
                              void* d_out, int out_size, void* d_ws, size_t ws_size,
                              hipStream_t stream) {
    const float* coords  = (const float*)d_in[0];
    const float* tplanes = (const float*)d_in[1];
    float* out = (float*)d_out;

    int M = in_sizes[0] / 3;                 // 524288
    size_t need = (size_t)NCELLS * 4 + (size_t)M * 16;

    if (ws_size < need) {
        int total = M * 3 * (FDIM / 4);
        k_direct<<<(total + 255) / 256, 256, 0, stream>>>(coords, tplanes, out, M);
        return;
    }

    unsigned* hist = (unsigned*)d_ws;                         // 16 KB
    float4* scoords = (float4*)((char*)d_ws + NCELLS * 4);    // M * 16 B

    (void)hipMemsetAsync(hist, 0, NCELLS * 4, stream);

    int pb = (M + 255) / 256;
    k_hist<<<pb, 256, 0, stream>>>(coords, hist, M);
    k_scan<<<1, 1024, 0, stream>>>(hist);
    k_scatter<<<pb, 256, 0, stream>>>(coords, hist, scoords, M);

    int total = M * 3 * (FDIM / 4);          // 12,582,912
    int nb = total / 256;                    // 49152, divisible by 8
    k_main<<<nb, 256, 0, stream>>>(scoords, tplanes, out, M);
}